// Round 4
// baseline (474.375 us; speedup 1.0000x reference)
//
#include <hip/hip_runtime.h>

#define NPTS      1048576
#define TABLE_SZ  1048577
#define NLEVELS   3
#define FDIM      8

// Persistent-style grid-stride kernel, 8 lanes per point (lane c = corner).
// 1-deep software pipeline: while consuming point t's 6 gathers, the
// indices + coord for point t+1 are already in flight, so each wave keeps
// gathers outstanding continuously (no dead index-load hop, no relaunch).
#define NBLOCKS 2048
#define PTS_PER_SWEEP ((NBLOCKS * 256) / 8)   // 65536
#define NITER (NPTS / PTS_PER_SWEEP)          // 16

__global__ __launch_bounds__(256, 8) void octree_persistent(
    const float* __restrict__ coord,     // (NPTS, 3)
    const float* __restrict__ features,  // (NLEVELS, TABLE_SZ, 8)
    const int*   __restrict__ indices,   // (NLEVELS, NPTS, 8)
    float*       __restrict__ out)       // (NPTS, 8)
{
    const int tid = blockIdx.x * blockDim.x + threadIdx.x;
    const int c   = tid & 7;        // corner 0..7
    int p = tid >> 3;               // first point for this lane group

    // ---- prologue: prefetch indices + coord for first point ----
    int   idx_c[NLEVELS];
    float cx_c, cy_c, cz_c;
    #pragma unroll
    for (int i = 0; i < NLEVELS; ++i)
        idx_c[i] = indices[(size_t)i * (size_t)NPTS * 8 + (size_t)p * 8 + c];
    cx_c = coord[3 * p + 0];
    cy_c = coord[3 * p + 1];
    cz_c = coord[3 * p + 2];

    for (int it = 0; it < NITER; ++it) {
        // ---- issue this point's 6 gathers first (front of vmem queue) ----
        float4 ga[NLEVELS], gb[NLEVELS];
        #pragma unroll
        for (int i = 0; i < NLEVELS; ++i) {
            const float* ft = features + (size_t)(NLEVELS - 1 - i) * (size_t)TABLE_SZ * FDIM;
            const float4* gp = reinterpret_cast<const float4*>(ft + (size_t)idx_c[i] * FDIM);
            ga[i] = gp[0];
            gb[i] = gp[1];
        }

        // ---- prefetch NEXT point's indices + coord (behind the gathers) ----
        const int pn = p + PTS_PER_SWEEP;
        int   idx_n[NLEVELS];
        float cx_n = 0.f, cy_n = 0.f, cz_n = 0.f;
        if (it + 1 < NITER) {
            #pragma unroll
            for (int i = 0; i < NLEVELS; ++i)
                idx_n[i] = indices[(size_t)i * (size_t)NPTS * 8 + (size_t)pn * 8 + c];
            cx_n = coord[3 * pn + 0];
            cy_n = coord[3 * pn + 1];
            cz_n = coord[3 * pn + 2];
        } else {
            #pragma unroll
            for (int i = 0; i < NLEVELS; ++i) idx_n[i] = 0;
        }

        // ---- weights (VALU, overlaps gather latency) ----
        float w[NLEVELS];
        #pragma unroll
        for (int i = 0; i < NLEVELS; ++i) {
            const float scale = (float)(2048 >> i);   // 2^(level-1), level = 12-i
            float fx = fmaf(scale, cx_c, scale);
            float fy = fmaf(scale, cy_c, scale);
            float fz = fmaf(scale, cz_c, scale);
            float dx = fx - floorf(fx);
            float dy = fy - floorf(fy);
            float dz = fz - floorf(fz);
            dx = dx * dx * (3.0f - 2.0f * dx);
            dy = dy * dy * (3.0f - 2.0f * dy);
            dz = dz * dz * (3.0f - 2.0f * dz);
            float wi = ((c & 4) ? dx : 1.0f - dx)
                     * ((c & 2) ? dy : 1.0f - dy)
                     * ((c & 1) ? dz : 1.0f - dz);
            w[i] = (idx_c[i] == TABLE_SZ - 1) ? 0.0f : wi;
        }

        // ---- weighted accumulate (waits only on the 6 gathers) ----
        float acc[FDIM];
        #pragma unroll
        for (int d = 0; d < FDIM; ++d) acc[d] = 0.0f;
        #pragma unroll
        for (int i = 0; i < NLEVELS; ++i) {
            acc[0] = fmaf(w[i], ga[i].x, acc[0]);
            acc[1] = fmaf(w[i], ga[i].y, acc[1]);
            acc[2] = fmaf(w[i], ga[i].z, acc[2]);
            acc[3] = fmaf(w[i], ga[i].w, acc[3]);
            acc[4] = fmaf(w[i], gb[i].x, acc[4]);
            acc[5] = fmaf(w[i], gb[i].y, acc[5]);
            acc[6] = fmaf(w[i], gb[i].z, acc[6]);
            acc[7] = fmaf(w[i], gb[i].w, acc[7]);
        }

        // ---- 3-round shfl_xor transpose-reduce; lane c ends with elem c ----
        const int b0 = c & 1, b1 = (c >> 1) & 1, b2 = (c >> 2) & 1;
        float s4[4];
        #pragma unroll
        for (int j = 0; j < 4; ++j) {
            float snd  = b0 ? acc[2 * j] : acc[2 * j + 1];
            float got  = __shfl_xor(snd, 1);
            float kept = b0 ? acc[2 * j + 1] : acc[2 * j];
            s4[j] = kept + got;
        }
        float s2[2];
        #pragma unroll
        for (int j = 0; j < 2; ++j) {
            float snd  = b1 ? s4[2 * j] : s4[2 * j + 1];
            float got  = __shfl_xor(snd, 2);
            float kept = b1 ? s4[2 * j + 1] : s4[2 * j];
            s2[j] = kept + got;
        }
        float snd  = b2 ? s2[0] : s2[1];
        float got  = __shfl_xor(snd, 4);
        float kept = b2 ? s2[1] : s2[0];
        out[(size_t)p * FDIM + c] = kept + got;   // coalesced 256B per wave

        // ---- rotate pipeline registers ----
        p = pn;
        #pragma unroll
        for (int i = 0; i < NLEVELS; ++i) idx_c[i] = idx_n[i];
        cx_c = cx_n; cy_c = cy_n; cz_c = cz_n;
    }
}

extern "C" void kernel_launch(void* const* d_in, const int* in_sizes, int n_in,
                              void* d_out, int out_size, void* d_ws, size_t ws_size,
                              hipStream_t stream) {
    const float* coord    = (const float*)d_in[0];
    const float* features = (const float*)d_in[1];
    const int*   indices  = (const int*)d_in[2];
    float*       out      = (float*)d_out;

    octree_persistent<<<NBLOCKS, 256, 0, stream>>>(coord, features, indices, out);
}